// Round 5
// baseline (202.509 us; speedup 1.0000x reference)
//
#include <hip/hip_runtime.h>
#include <hip/hip_bf16.h>
#include <math.h>

#define BN 4
#define CIN 128
#define COUT 64
#define WSDIM 512
#define HI 128
#define WI 128
#define HO 256
#define WO 256
#define EPSC 1e-8f
#define GAINC 1.3867504905630728f
#define HE1 (GAINC/33.941125496954285f)
#define HE2 (GAINC/24.0f)
#define SUP (127.0f/255.0f)

typedef __attribute__((ext_vector_type(8))) short s16x8;
typedef __attribute__((ext_vector_type(4))) float f32x4_t;
typedef __attribute__((ext_vector_type(4))) unsigned int u32x4;

static __device__ __forceinline__ float lrelu(float v){ return v > 0.f ? v : 0.2f*v; }
static __device__ __forceinline__ unsigned short bfbits(float v){
  __hip_bfloat16 h = __float2bfloat16(v);
  return *reinterpret_cast<unsigned short*>(&h);
}
static __device__ __forceinline__ unsigned int packbf(float a, float b){
  return (unsigned int)bfbits(a) | ((unsigned int)bfbits(b) << 16);
}

// ---------------- fused prep: B-fragments (g<288) + styles/demod (g>=288) ----------------
__global__ __launch_bounds__(256) void k_prep(
    const float* __restrict__ w, const float* __restrict__ c1w, const float* __restrict__ c2w,
    const float* __restrict__ a1w, const float* __restrict__ a1b,
    const float* __restrict__ a2w, const float* __restrict__ a2b,
    unsigned short* __restrict__ B1, unsigned short* __restrict__ B2,
    float* __restrict__ s1, float* __restrict__ s2,
    float* __restrict__ d1g, float* __restrict__ d2g)
{
  const int g = blockIdx.x, t = threadIdx.x;
  __shared__ float sh1[CIN];
  __shared__ float sh2[COUT];
  if (g < 144) {
    int cc = g / 36, r = g - cc * 36, k = r >> 2, ot = r & 3;
    for (int e = t; e < 512; e += 256) {
      int l = e >> 3, j = e & 7;
      int c = cc * 32 + (l >> 4) * 8 + j, o = ot * 16 + (l & 15);
      B1[g * 512 + e] = bfbits(c1w[(c * COUT + o) * 9 + (8 - k)] * HE1);
    }
  } else if (g < 288) {
    int g2 = g - 144;
    int cc = g2 / 36, r = g2 - cc * 36, k = r >> 2, ot = r & 3;
    for (int e = t; e < 512; e += 256) {
      int l = e >> 3, j = e & 7;
      int c = cc * 32 + (l >> 4) * 8 + j, o = ot * 16 + (l & 15);
      B2[g2 * 512 + e] = bfbits(c2w[(c * COUT + o) * 9 + (8 - k)] * HE2);
    }
  } else {
    const int b = g - 288;
    const float he_a = 0.044194173824159216f;
    const float* wv = w + b * WSDIM;
    if (t < CIN) {
      float acc = 0.f;
      const float* ap = a1w + t * WSDIM;
      for (int k = 0; k < WSDIM; ++k) acc += ap[k] * wv[k];
      float v = acc * he_a + a1b[t];
      sh1[t] = v; s1[b * CIN + t] = v;
    } else if (t < CIN + COUT) {
      int o = t - CIN;
      float acc = 0.f;
      const float* ap = a2w + o * WSDIM;
      for (int k = 0; k < WSDIM; ++k) acc += ap[k] * wv[k];
      float v = acc * he_a + a2b[o];
      sh2[o] = v; s2[b * COUT + o] = v;
    }
    __syncthreads();
    const int o = t >> 2, p = t & 3;
    float acc = 0.f;
    for (int c = p * 32; c < p * 32 + 32; ++c) {
      const float* wp = c1w + (size_t)(c * COUT + o) * 9;
      float ws_ = 0.f;
      #pragma unroll
      for (int k = 0; k < 9; ++k) ws_ += wp[k] * wp[k];
      acc += sh1[c] * sh1[c] * ws_;
    }
    acc += __shfl_xor(acc, 1); acc += __shfl_xor(acc, 2);
    if (p == 0) d1g[b * COUT + o] = rsqrtf(acc * HE1 * HE1 + EPSC) * GAINC;
    float ac2 = 0.f;
    for (int c = p * 16; c < p * 16 + 16; ++c) {
      const float* wp = c2w + (size_t)(c * COUT + o) * 9;
      float ws_ = 0.f;
      #pragma unroll
      for (int k = 0; k < 9; ++k) ws_ += wp[k] * wp[k];
      ac2 += sh2[c] * sh2[c] * ws_;
    }
    ac2 += __shfl_xor(ac2, 1); ac2 += __shfl_xor(ac2, 2);
    if (p == 0) d2g[b * COUT + o] = rsqrtf(ac2 * HE2 * HE2 + EPSC) * GAINC;
  }
}

// ---------------- k_up: LDS-staged transpose; coalesced both sides ----------------
__global__ __launch_bounds__(256) void k_up(
    const float* __restrict__ x, const float* __restrict__ s1, unsigned short* __restrict__ XU)
{
  const int bid = blockIdx.x;
  const int swz = (bid & 7) * 128 + (bid >> 3);
  const int b = swz >> 8, yo = swz & 255;
  const int tid = threadIdx.x;
  __shared__ float xs[2][128][36];

  const float fy = yo * SUP;
  const int y0 = (int)fy;
  const float wy = fy - (float)y0;
  const int y1 = min(y0 + 1, HI - 1);

  const float* xb = x + ((size_t)b * CIN << 14);
  unsigned short* outb = XU + (((size_t)b * HO + yo) * WO) * (size_t)CIN;
  const int ch0 = (tid & 3) * 8;

  for (int chunk = 0; chunk < 4; ++chunk) {
    if (chunk) __syncthreads();
    #pragma unroll
    for (int i = 0; i < 2; ++i) {
      int rid = i * 32 + (tid >> 3);
      int c = rid >> 1, r = rid & 1;
      const float* src = xb + (((size_t)(chunk * 32 + c)) << 14) + (r ? y1 : y0) * WI + (tid & 7) * 4;
      #pragma unroll
      for (int k = 0; k < 4; ++k) {
        f32x4_t v = *(const f32x4_t*)(src + k * 32);
        int xp = (tid & 7) * 4 + k * 32;
        xs[r][xp + 0][c] = v[0];
        xs[r][xp + 1][c] = v[1];
        xs[r][xp + 2][c] = v[2];
        xs[r][xp + 3][c] = v[3];
      }
    }
    f32x4_t sA = *(const f32x4_t*)(s1 + b * CIN + chunk * 32 + ch0);
    f32x4_t sB = *(const f32x4_t*)(s1 + b * CIN + chunk * 32 + ch0 + 4);
    __syncthreads();
    #pragma unroll
    for (int pp = 0; pp < 4; ++pp) {
      int pix = pp * 64 + (tid >> 2);
      float fx = pix * SUP;
      int x0 = (int)fx;
      float wx = fx - (float)x0;
      int x1 = min(x0 + 1, WI - 1);

      f32x4_t a0A = *(const f32x4_t*)&xs[0][x0][ch0];
      f32x4_t a1A = *(const f32x4_t*)&xs[0][x1][ch0];
      f32x4_t c0A = *(const f32x4_t*)&xs[1][x0][ch0];
      f32x4_t c1A = *(const f32x4_t*)&xs[1][x1][ch0];
      f32x4_t a0B = *(const f32x4_t*)&xs[0][x0][ch0 + 4];
      f32x4_t a1B = *(const f32x4_t*)&xs[0][x1][ch0 + 4];
      f32x4_t c0B = *(const f32x4_t*)&xs[1][x0][ch0 + 4];
      f32x4_t c1B = *(const f32x4_t*)&xs[1][x1][ch0 + 4];

      float vv[8];
      #pragma unroll
      for (int e = 0; e < 4; ++e) {
        float t0 = a0A[e] + (c0A[e] - a0A[e]) * wy;
        float t1 = a1A[e] + (c1A[e] - a1A[e]) * wy;
        vv[e] = (t0 + (t1 - t0) * wx) * sA[e];
      }
      #pragma unroll
      for (int e = 0; e < 4; ++e) {
        float t0 = a0B[e] + (c0B[e] - a0B[e]) * wy;
        float t1 = a1B[e] + (c1B[e] - a1B[e]) * wy;
        vv[4 + e] = (t0 + (t1 - t0) * wx) * sB[e];
      }
      unsigned int pk[4];
      pk[0] = packbf(vv[0], vv[1]); pk[1] = packbf(vv[2], vv[3]);
      pk[2] = packbf(vv[4], vv[5]); pk[3] = packbf(vv[6], vv[7]);
      *(u32x4*)(outb + (size_t)pix * CIN + chunk * 32 + ch0) = *(u32x4*)pk;
    }
  }
}

// ---------------- conv1: LDS double-buffer, 1 barrier/phase, prefetch across barrier ----------------
__global__ __launch_bounds__(256, 3) void k_conv1(
    const unsigned short* __restrict__ XU, const unsigned short* __restrict__ B1pre,
    const float* __restrict__ noise1, const float* __restrict__ bias1, const float* __restrict__ baff1,
    const float* __restrict__ d1g, const float* __restrict__ s2,
    unsigned short* __restrict__ h1)
{
  const int b = blockIdx.z;
  const int oy0 = blockIdx.y * 16, ox0 = blockIdx.x * 16;
  const int tid = threadIdx.x;
  const int lane = tid & 63, wv = tid >> 6;
  const int lx = lane & 15, lg = lane >> 4;

  __shared__ unsigned int ldsA[2][324 * 20];

  f32x4_t acc[4][4];
  #pragma unroll
  for (int i = 0; i < 4; ++i)
    #pragma unroll
    for (int j = 0; j < 4; ++j) acc[i][j] = (f32x4_t){0.f, 0.f, 0.f, 0.f};

  const s16x8* Bb = (const s16x8*)B1pre;

  u32x4 rg[6];
  auto LOAD = [&](int cc) {
    #pragma unroll
    for (int i = 0; i < 6; ++i) {
      int e = i * 256 + tid;
      u32x4 v = {0, 0, 0, 0};
      if (e < 1296) {
        int pos = e >> 2, q = e & 3;
        int ys = pos / 18, xs = pos - ys * 18;
        int yy = oy0 - 1 + ys, xx = ox0 - 1 + xs;
        if (yy >= 0 && yy < HO && xx >= 0 && xx < WO)
          v = *(const u32x4*)(XU + ((((size_t)b * HO + yy) * WO + xx) * CIN + cc * 32 + q * 8));
      }
      rg[i] = v;
    }
  };
  auto STORE = [&](unsigned int* buf) {
    #pragma unroll
    for (int i = 0; i < 6; ++i) {
      int e = i * 256 + tid;
      if (e < 1296) {
        int pos = e >> 2, q = e & 3;
        *(u32x4*)(buf + pos * 20 + q * 4) = rg[i];
      }
    }
  };

  LOAD(0);
  for (int cc = 0; cc < 4; ++cc) {
    STORE(&ldsA[cc & 1][0]);
    if (cc < 3) LOAD(cc + 1);                 // prefetch: stays in flight across barrier
    asm volatile("s_waitcnt lgkmcnt(0)" ::: "memory");
    __builtin_amdgcn_s_barrier();
    asm volatile("" ::: "memory");
    const unsigned int* buf = &ldsA[cc & 1][0];
    #pragma unroll
    for (int k = 0; k < 9; ++k) {
      const int dy = k / 3, dx = k - 3 * (k / 3);
      s16x8 b0 = Bb[((cc * 9 + k) * 4 + 0) * 64 + lane];
      s16x8 b1 = Bb[((cc * 9 + k) * 4 + 1) * 64 + lane];
      s16x8 b2 = Bb[((cc * 9 + k) * 4 + 2) * 64 + lane];
      s16x8 b3 = Bb[((cc * 9 + k) * 4 + 3) * 64 + lane];
      #pragma unroll
      for (int yi = 0; yi < 4; ++yi) {
        int row = (wv * 4 + yi + dy) * 18 + (lx + dx);
        s16x8 a = *(const s16x8*)((const char*)buf + (size_t)row * 80 + lg * 16);
        acc[yi][0] = __builtin_amdgcn_mfma_f32_16x16x32_bf16(a, b0, acc[yi][0], 0, 0, 0);
        acc[yi][1] = __builtin_amdgcn_mfma_f32_16x16x32_bf16(a, b1, acc[yi][1], 0, 0, 0);
        acc[yi][2] = __builtin_amdgcn_mfma_f32_16x16x32_bf16(a, b2, acc[yi][2], 0, 0, 0);
        acc[yi][3] = __builtin_amdgcn_mfma_f32_16x16x32_bf16(a, b3, acc[yi][3], 0, 0, 0);
      }
    }
  }
  #pragma unroll
  for (int yi = 0; yi < 4; ++yi) {
    int y = oy0 + wv * 4 + yi;
    f32x4_t nv = *(const f32x4_t*)(noise1 + (size_t)b * HO * WO + (size_t)y * WO + ox0 + lg * 4);
    #pragma unroll
    for (int ot = 0; ot < 4; ++ot) {
      int o = ot * 16 + lx;
      float d = d1g[b * COUT + o], ba = baff1[o], bi = bias1[o], sv = s2[b * COUT + o];
      #pragma unroll
      for (int jj = 0; jj < 4; ++jj) {
        float v = acc[yi][ot][jj] * d + nv[jj] * ba + bi;
        v = lrelu(v) * sv;
        int xg = ox0 + lg * 4 + jj;
        h1[(((size_t)b * HO + y) * WO + xg) * COUT + o] = bfbits(v);
      }
    }
  }
}

// ---------------- conv2: same structure + fused rgb ----------------
__global__ __launch_bounds__(256, 3) void k_conv2(
    const unsigned short* __restrict__ h1, const unsigned short* __restrict__ B2pre,
    const float* __restrict__ noise2, const float* __restrict__ bias2, const float* __restrict__ baff2,
    const float* __restrict__ d2g, const float* __restrict__ rgbw, const float* __restrict__ rgbb,
    float* __restrict__ hout, float* __restrict__ rgbout)
{
  const int b = blockIdx.z;
  const int oy0 = blockIdx.y * 16, ox0 = blockIdx.x * 16;
  const int tid = threadIdx.x;
  const int lane = tid & 63, wv = tid >> 6;
  const int lx = lane & 15, lg = lane >> 4;

  __shared__ unsigned int ldsA[2][324 * 20];

  f32x4_t acc[4][4];
  #pragma unroll
  for (int i = 0; i < 4; ++i)
    #pragma unroll
    for (int j = 0; j < 4; ++j) acc[i][j] = (f32x4_t){0.f, 0.f, 0.f, 0.f};

  const s16x8* Bb = (const s16x8*)B2pre;

  u32x4 rg[6];
  auto LOAD = [&](int cc) {
    #pragma unroll
    for (int i = 0; i < 6; ++i) {
      int e = i * 256 + tid;
      u32x4 v = {0, 0, 0, 0};
      if (e < 1296) {
        int pos = e >> 2, q = e & 3;
        int ys = pos / 18, xs = pos - ys * 18;
        int yy = oy0 - 1 + ys, xx = ox0 - 1 + xs;
        if (yy >= 0 && yy < HO && xx >= 0 && xx < WO)
          v = *(const u32x4*)(h1 + ((((size_t)b * HO + yy) * WO + xx) * COUT + cc * 32 + q * 8));
      }
      rg[i] = v;
    }
  };
  auto STORE = [&](unsigned int* buf) {
    #pragma unroll
    for (int i = 0; i < 6; ++i) {
      int e = i * 256 + tid;
      if (e < 1296) {
        int pos = e >> 2, q = e & 3;
        *(u32x4*)(buf + pos * 20 + q * 4) = rg[i];
      }
    }
  };

  LOAD(0);
  for (int cc = 0; cc < 2; ++cc) {
    STORE(&ldsA[cc & 1][0]);
    if (cc < 1) LOAD(cc + 1);
    asm volatile("s_waitcnt lgkmcnt(0)" ::: "memory");
    __builtin_amdgcn_s_barrier();
    asm volatile("" ::: "memory");
    const unsigned int* buf = &ldsA[cc & 1][0];
    #pragma unroll
    for (int k = 0; k < 9; ++k) {
      const int dy = k / 3, dx = k - 3 * (k / 3);
      s16x8 b0 = Bb[((cc * 9 + k) * 4 + 0) * 64 + lane];
      s16x8 b1 = Bb[((cc * 9 + k) * 4 + 1) * 64 + lane];
      s16x8 b2 = Bb[((cc * 9 + k) * 4 + 2) * 64 + lane];
      s16x8 b3 = Bb[((cc * 9 + k) * 4 + 3) * 64 + lane];
      #pragma unroll
      for (int yi = 0; yi < 4; ++yi) {
        int row = (wv * 4 + yi + dy) * 18 + (lx + dx);
        s16x8 a = *(const s16x8*)((const char*)buf + (size_t)row * 80 + lg * 16);
        acc[yi][0] = __builtin_amdgcn_mfma_f32_16x16x32_bf16(a, b0, acc[yi][0], 0, 0, 0);
        acc[yi][1] = __builtin_amdgcn_mfma_f32_16x16x32_bf16(a, b1, acc[yi][1], 0, 0, 0);
        acc[yi][2] = __builtin_amdgcn_mfma_f32_16x16x32_bf16(a, b2, acc[yi][2], 0, 0, 0);
        acc[yi][3] = __builtin_amdgcn_mfma_f32_16x16x32_bf16(a, b3, acc[yi][3], 0, 0, 0);
      }
    }
  }
  const float her = 0.03f / 8.0f;
  #pragma unroll
  for (int yi = 0; yi < 4; ++yi) {
    int y = oy0 + wv * 4 + yi;
    f32x4_t nv = *(const f32x4_t*)(noise2 + (size_t)b * HO * WO + (size_t)y * WO + ox0 + lg * 4);
    float r[3][4];
    #pragma unroll
    for (int ch = 0; ch < 3; ++ch)
      #pragma unroll
      for (int jj = 0; jj < 4; ++jj) r[ch][jj] = 0.f;
    #pragma unroll
    for (int ot = 0; ot < 4; ++ot) {
      int o = ot * 16 + lx;
      float d = d2g[b * COUT + o], ba = baff2[o], bi = bias2[o];
      float w0 = rgbw[o], w1 = rgbw[COUT + o], w2 = rgbw[2 * COUT + o];
      f32x4_t hv;
      #pragma unroll
      for (int jj = 0; jj < 4; ++jj) {
        float v = acc[yi][ot][jj] * d + nv[jj] * ba + bi;
        v = lrelu(v);
        hv[jj] = v;
        r[0][jj] += w0 * v; r[1][jj] += w1 * v; r[2][jj] += w2 * v;
      }
      *(f32x4_t*)(hout + ((size_t)(b * COUT + o) * HO + y) * WO + ox0 + lg * 4) = hv;
    }
    #pragma unroll
    for (int ch = 0; ch < 3; ++ch)
      #pragma unroll
      for (int jj = 0; jj < 4; ++jj) {
        float s = r[ch][jj];
        s += __shfl_xor(s, 1); s += __shfl_xor(s, 2);
        s += __shfl_xor(s, 4); s += __shfl_xor(s, 8);
        r[ch][jj] = s;
      }
    if (lx < 12) {
      float val = 0.f;
      #pragma unroll
      for (int ii = 0; ii < 12; ++ii) if (lx == ii) val = r[ii >> 2][ii & 3];
      int ch = lx >> 2, jj = lx & 3;
      rgbout[(((size_t)(b * 3 + ch)) * HO + y) * WO + ox0 + lg * 4 + jj] = val * her + rgbb[ch];
    }
  }
}

extern "C" void kernel_launch(void* const* d_in, const int* in_sizes, int n_in,
                              void* d_out, int out_size, void* d_ws, size_t ws_size,
                              hipStream_t stream) {
  const float* x      = (const float*)d_in[0];
  const float* w      = (const float*)d_in[1];
  const float* c1w    = (const float*)d_in[2];
  const float* c2w    = (const float*)d_in[3];
  const float* bias1  = (const float*)d_in[4];
  const float* bias2  = (const float*)d_in[5];
  const float* a1w    = (const float*)d_in[6];
  const float* a1b    = (const float*)d_in[7];
  const float* a2w    = (const float*)d_in[8];
  const float* a2b    = (const float*)d_in[9];
  const float* baff1  = (const float*)d_in[10];
  const float* baff2  = (const float*)d_in[11];
  const float* rgbw   = (const float*)d_in[12];
  const float* rgbb   = (const float*)d_in[13];
  const float* noise1 = (const float*)d_in[14];
  const float* noise2 = (const float*)d_in[15];

  const size_t h1_bytes = (size_t)BN * HO * WO * COUT * 2;   // 32 MiB
  unsigned short* h1 = (unsigned short*)d_ws;
  char* p = (char*)d_ws + h1_bytes;
  float* s1  = (float*)p;               p += BN * CIN * 4;
  float* s2  = (float*)p;               p += BN * COUT * 4;
  float* d1g = (float*)p;               p += BN * COUT * 4;
  float* d2g = (float*)p;               p += BN * COUT * 4;
  unsigned short* B1pre = (unsigned short*)p;  p += 144 * 512 * 2;
  unsigned short* B2pre = (unsigned short*)p;

  // XU (bf16 channel-last, 64 MiB) lives in d_out; dead before conv2 writes hout.
  unsigned short* XU = (unsigned short*)d_out;
  float* hout   = (float*)d_out;
  float* rgbout = hout + (size_t)BN * COUT * HO * WO;

  k_prep<<<292, 256, 0, stream>>>(w, c1w, c2w, a1w, a1b, a2w, a2b, B1pre, B2pre, s1, s2, d1g, d2g);
  k_up<<<BN * HO, 256, 0, stream>>>(x, s1, XU);
  dim3 grid(WO / 16, HO / 16, BN);
  k_conv1<<<grid, 256, 0, stream>>>(XU, B1pre, noise1, bias1, baff1, d1g, s2, h1);
  k_conv2<<<grid, 256, 0, stream>>>(h1, B2pre, noise2, bias2, baff2, d2g, rgbw, rgbb, hout, rgbout);
}

// Round 6
// 193.854 us; speedup vs baseline: 1.0446x; 1.0446x over previous
//
#include <hip/hip_runtime.h>
#include <hip/hip_bf16.h>
#include <math.h>

#define BN 4
#define CIN 128
#define COUT 64
#define WSDIM 512
#define HI 128
#define WI 128
#define HO 256
#define WO 256
#define EPSC 1e-8f
#define GAINC 1.3867504905630728f
#define HE1 (GAINC/33.941125496954285f)
#define HE2 (GAINC/24.0f)
#define SUP (127.0f/255.0f)

typedef __attribute__((ext_vector_type(8))) short s16x8;
typedef __attribute__((ext_vector_type(4))) float f32x4_t;
typedef __attribute__((ext_vector_type(4))) unsigned int u32x4;

static __device__ __forceinline__ float lrelu(float v){ return v > 0.f ? v : 0.2f*v; }
static __device__ __forceinline__ unsigned short bfbits(float v){
  __hip_bfloat16 h = __float2bfloat16(v);
  return *reinterpret_cast<unsigned short*>(&h);
}
static __device__ __forceinline__ unsigned int packbf(float a, float b){
  return (unsigned int)bfbits(a) | ((unsigned int)bfbits(b) << 16);
}

// ---------------- fused prep: B-fragments (g<288) + styles/demod (g>=288) ----------------
__global__ __launch_bounds__(256) void k_prep(
    const float* __restrict__ w, const float* __restrict__ c1w, const float* __restrict__ c2w,
    const float* __restrict__ a1w, const float* __restrict__ a1b,
    const float* __restrict__ a2w, const float* __restrict__ a2b,
    unsigned short* __restrict__ B1, unsigned short* __restrict__ B2,
    float* __restrict__ s1, float* __restrict__ s2,
    float* __restrict__ d1g, float* __restrict__ d2g)
{
  const int g = blockIdx.x, t = threadIdx.x;
  __shared__ float sh1[CIN];
  __shared__ float sh2[COUT];
  if (g < 144) {
    int cc = g / 36, r = g - cc * 36, k = r >> 2, ot = r & 3;
    for (int e = t; e < 512; e += 256) {
      int l = e >> 3, j = e & 7;
      int c = cc * 32 + (l >> 4) * 8 + j, o = ot * 16 + (l & 15);
      B1[g * 512 + e] = bfbits(c1w[(c * COUT + o) * 9 + (8 - k)] * HE1);
    }
  } else if (g < 288) {
    int g2 = g - 144;
    int cc = g2 / 36, r = g2 - cc * 36, k = r >> 2, ot = r & 3;
    for (int e = t; e < 512; e += 256) {
      int l = e >> 3, j = e & 7;
      int c = cc * 32 + (l >> 4) * 8 + j, o = ot * 16 + (l & 15);
      B2[g2 * 512 + e] = bfbits(c2w[(c * COUT + o) * 9 + (8 - k)] * HE2);
    }
  } else {
    const int b = g - 288;
    const float he_a = 0.044194173824159216f;
    const float* wv = w + b * WSDIM;
    if (t < CIN) {
      float acc = 0.f;
      const float* ap = a1w + t * WSDIM;
      for (int k = 0; k < WSDIM; ++k) acc += ap[k] * wv[k];
      float v = acc * he_a + a1b[t];
      sh1[t] = v; s1[b * CIN + t] = v;
    } else if (t < CIN + COUT) {
      int o = t - CIN;
      float acc = 0.f;
      const float* ap = a2w + o * WSDIM;
      for (int k = 0; k < WSDIM; ++k) acc += ap[k] * wv[k];
      float v = acc * he_a + a2b[o];
      sh2[o] = v; s2[b * COUT + o] = v;
    }
    __syncthreads();
    const int o = t >> 2, p = t & 3;
    float acc = 0.f;
    for (int c = p * 32; c < p * 32 + 32; ++c) {
      const float* wp = c1w + (size_t)(c * COUT + o) * 9;
      float ws_ = 0.f;
      #pragma unroll
      for (int k = 0; k < 9; ++k) ws_ += wp[k] * wp[k];
      acc += sh1[c] * sh1[c] * ws_;
    }
    acc += __shfl_xor(acc, 1); acc += __shfl_xor(acc, 2);
    if (p == 0) d1g[b * COUT + o] = rsqrtf(acc * HE1 * HE1 + EPSC) * GAINC;
    float ac2 = 0.f;
    for (int c = p * 16; c < p * 16 + 16; ++c) {
      const float* wp = c2w + (size_t)(c * COUT + o) * 9;
      float ws_ = 0.f;
      #pragma unroll
      for (int k = 0; k < 9; ++k) ws_ += wp[k] * wp[k];
      ac2 += sh2[c] * sh2[c] * ws_;
    }
    ac2 += __shfl_xor(ac2, 1); ac2 += __shfl_xor(ac2, 2);
    if (p == 0) d2g[b * COUT + o] = rsqrtf(ac2 * HE2 * HE2 + EPSC) * GAINC;
  }
}

// ---------------- k_up: LDS-staged transpose; coalesced both sides ----------------
// XCD i writes XU band b=i/2, rows [(i&1)*128, +128).
__global__ __launch_bounds__(256) void k_up(
    const float* __restrict__ x, const float* __restrict__ s1, unsigned short* __restrict__ XU)
{
  const int bid = blockIdx.x;
  const int swz = (bid & 7) * 128 + (bid >> 3);
  const int b = swz >> 8, yo = swz & 255;
  const int tid = threadIdx.x;
  __shared__ float xs[2][128][36];

  const float fy = yo * SUP;
  const int y0 = (int)fy;
  const float wy = fy - (float)y0;
  const int y1 = min(y0 + 1, HI - 1);

  const float* xb = x + ((size_t)b * CIN << 14);
  unsigned short* outb = XU + (((size_t)b * HO + yo) * WO) * (size_t)CIN;
  const int ch0 = (tid & 3) * 8;

  for (int chunk = 0; chunk < 4; ++chunk) {
    if (chunk) __syncthreads();
    #pragma unroll
    for (int i = 0; i < 2; ++i) {
      int rid = i * 32 + (tid >> 3);
      int c = rid >> 1, r = rid & 1;
      const float* src = xb + (((size_t)(chunk * 32 + c)) << 14) + (r ? y1 : y0) * WI + (tid & 7) * 4;
      #pragma unroll
      for (int k = 0; k < 4; ++k) {
        f32x4_t v = *(const f32x4_t*)(src + k * 32);
        int xp = (tid & 7) * 4 + k * 32;
        xs[r][xp + 0][c] = v[0];
        xs[r][xp + 1][c] = v[1];
        xs[r][xp + 2][c] = v[2];
        xs[r][xp + 3][c] = v[3];
      }
    }
    f32x4_t sA = *(const f32x4_t*)(s1 + b * CIN + chunk * 32 + ch0);
    f32x4_t sB = *(const f32x4_t*)(s1 + b * CIN + chunk * 32 + ch0 + 4);
    __syncthreads();
    #pragma unroll
    for (int pp = 0; pp < 4; ++pp) {
      int pix = pp * 64 + (tid >> 2);
      float fx = pix * SUP;
      int x0 = (int)fx;
      float wx = fx - (float)x0;
      int x1 = min(x0 + 1, WI - 1);

      f32x4_t a0A = *(const f32x4_t*)&xs[0][x0][ch0];
      f32x4_t a1A = *(const f32x4_t*)&xs[0][x1][ch0];
      f32x4_t c0A = *(const f32x4_t*)&xs[1][x0][ch0];
      f32x4_t c1A = *(const f32x4_t*)&xs[1][x1][ch0];
      f32x4_t a0B = *(const f32x4_t*)&xs[0][x0][ch0 + 4];
      f32x4_t a1B = *(const f32x4_t*)&xs[0][x1][ch0 + 4];
      f32x4_t c0B = *(const f32x4_t*)&xs[1][x0][ch0 + 4];
      f32x4_t c1B = *(const f32x4_t*)&xs[1][x1][ch0 + 4];

      float vv[8];
      #pragma unroll
      for (int e = 0; e < 4; ++e) {
        float t0 = a0A[e] + (c0A[e] - a0A[e]) * wy;
        float t1 = a1A[e] + (c1A[e] - a1A[e]) * wy;
        vv[e] = (t0 + (t1 - t0) * wx) * sA[e];
      }
      #pragma unroll
      for (int e = 0; e < 4; ++e) {
        float t0 = a0B[e] + (c0B[e] - a0B[e]) * wy;
        float t1 = a1B[e] + (c1B[e] - a1B[e]) * wy;
        vv[4 + e] = (t0 + (t1 - t0) * wx) * sB[e];
      }
      unsigned int pk[4];
      pk[0] = packbf(vv[0], vv[1]); pk[1] = packbf(vv[2], vv[3]);
      pk[2] = packbf(vv[4], vv[5]); pk[3] = packbf(vv[6], vv[7]);
      *(u32x4*)(outb + (size_t)pix * CIN + chunk * 32 + ch0) = *(u32x4*)pk;
    }
  }
}

// ---------------- conv1: 2-barrier LDS dbuf; prefetch hidden under MFMA; XCD-aligned ----------------
__global__ __launch_bounds__(256, 3) void k_conv1(
    const unsigned short* __restrict__ XU, const unsigned short* __restrict__ B1pre,
    const float* __restrict__ noise1, const float* __restrict__ bias1, const float* __restrict__ baff1,
    const float* __restrict__ d1g, const float* __restrict__ s2,
    unsigned short* __restrict__ h1)
{
  const int id = blockIdx.x;
  const int swz = (id & 7) * 128 + (id >> 3);       // XCD k gets b=k/2, y-band (k&1)*8..+8
  const int b = swz >> 8;
  const int oy0 = ((swz >> 4) & 15) * 16, ox0 = (swz & 15) * 16;
  const int tid = threadIdx.x;
  const int lane = tid & 63, wv = tid >> 6;
  const int lx = lane & 15, lg = lane >> 4;

  __shared__ unsigned int ldsA[2][324 * 20];

  f32x4_t acc[4][4];
  #pragma unroll
  for (int i = 0; i < 4; ++i)
    #pragma unroll
    for (int j = 0; j < 4; ++j) acc[i][j] = (f32x4_t){0.f, 0.f, 0.f, 0.f};

  const s16x8* Bb = (const s16x8*)B1pre;

  u32x4 rg[6];
  auto LOAD = [&](int cc) {
    #pragma unroll
    for (int i = 0; i < 6; ++i) {
      int e = i * 256 + tid;
      u32x4 v = {0, 0, 0, 0};
      if (e < 1296) {
        int pos = e >> 2, q = e & 3;
        int ys = pos / 18, xs = pos - ys * 18;
        int yy = oy0 - 1 + ys, xx = ox0 - 1 + xs;
        if (yy >= 0 && yy < HO && xx >= 0 && xx < WO)
          v = *(const u32x4*)(XU + ((((size_t)b * HO + yy) * WO + xx) * CIN + cc * 32 + q * 8));
      }
      rg[i] = v;
    }
  };
  auto STORE = [&](unsigned int* buf) {
    #pragma unroll
    for (int i = 0; i < 6; ++i) {
      int e = i * 256 + tid;
      if (e < 1296) {
        int pos = e >> 2, q = e & 3;
        *(u32x4*)(buf + pos * 20 + q * 4) = rg[i];
      }
    }
  };

  LOAD(0);
  for (int cc = 0; cc < 4; ++cc) {
    if (cc) __syncthreads();                 // barrier A: readers of this buf are done
    STORE(&ldsA[cc & 1][0]);
    __syncthreads();                         // barrier B: buf visible (vmcnt drain cheap here)
    if (cc < 3) LOAD(cc + 1);                // prefetch issues now; drained at next barrier A
    const unsigned int* buf = &ldsA[cc & 1][0];
    #pragma unroll
    for (int k = 0; k < 9; ++k) {
      const int dy = k / 3, dx = k - 3 * (k / 3);
      s16x8 b0 = Bb[((cc * 9 + k) * 4 + 0) * 64 + lane];
      s16x8 b1 = Bb[((cc * 9 + k) * 4 + 1) * 64 + lane];
      s16x8 b2 = Bb[((cc * 9 + k) * 4 + 2) * 64 + lane];
      s16x8 b3 = Bb[((cc * 9 + k) * 4 + 3) * 64 + lane];
      #pragma unroll
      for (int yi = 0; yi < 4; ++yi) {
        int row = (wv * 4 + yi + dy) * 18 + (lx + dx);
        s16x8 a = *(const s16x8*)((const char*)buf + (size_t)row * 80 + lg * 16);
        acc[yi][0] = __builtin_amdgcn_mfma_f32_16x16x32_bf16(a, b0, acc[yi][0], 0, 0, 0);
        acc[yi][1] = __builtin_amdgcn_mfma_f32_16x16x32_bf16(a, b1, acc[yi][1], 0, 0, 0);
        acc[yi][2] = __builtin_amdgcn_mfma_f32_16x16x32_bf16(a, b2, acc[yi][2], 0, 0, 0);
        acc[yi][3] = __builtin_amdgcn_mfma_f32_16x16x32_bf16(a, b3, acc[yi][3], 0, 0, 0);
      }
    }
  }
  #pragma unroll
  for (int yi = 0; yi < 4; ++yi) {
    int y = oy0 + wv * 4 + yi;
    f32x4_t nv = *(const f32x4_t*)(noise1 + (size_t)b * HO * WO + (size_t)y * WO + ox0 + lg * 4);
    #pragma unroll
    for (int ot = 0; ot < 4; ++ot) {
      int o = ot * 16 + lx;
      float d = d1g[b * COUT + o], ba = baff1[o], bi = bias1[o], sv = s2[b * COUT + o];
      #pragma unroll
      for (int jj = 0; jj < 4; ++jj) {
        float v = acc[yi][ot][jj] * d + nv[jj] * ba + bi;
        v = lrelu(v) * sv;
        int xg = ox0 + lg * 4 + jj;
        h1[(((size_t)b * HO + y) * WO + xg) * COUT + o] = bfbits(v);
      }
    }
  }
}

// ---------------- conv2: same structure + fused rgb ----------------
__global__ __launch_bounds__(256, 3) void k_conv2(
    const unsigned short* __restrict__ h1, const unsigned short* __restrict__ B2pre,
    const float* __restrict__ noise2, const float* __restrict__ bias2, const float* __restrict__ baff2,
    const float* __restrict__ d2g, const float* __restrict__ rgbw, const float* __restrict__ rgbb,
    float* __restrict__ hout, float* __restrict__ rgbout)
{
  const int id = blockIdx.x;
  const int swz = (id & 7) * 128 + (id >> 3);
  const int b = swz >> 8;
  const int oy0 = ((swz >> 4) & 15) * 16, ox0 = (swz & 15) * 16;
  const int tid = threadIdx.x;
  const int lane = tid & 63, wv = tid >> 6;
  const int lx = lane & 15, lg = lane >> 4;

  __shared__ unsigned int ldsA[2][324 * 20];

  f32x4_t acc[4][4];
  #pragma unroll
  for (int i = 0; i < 4; ++i)
    #pragma unroll
    for (int j = 0; j < 4; ++j) acc[i][j] = (f32x4_t){0.f, 0.f, 0.f, 0.f};

  const s16x8* Bb = (const s16x8*)B2pre;

  u32x4 rg[6];
  auto LOAD = [&](int cc) {
    #pragma unroll
    for (int i = 0; i < 6; ++i) {
      int e = i * 256 + tid;
      u32x4 v = {0, 0, 0, 0};
      if (e < 1296) {
        int pos = e >> 2, q = e & 3;
        int ys = pos / 18, xs = pos - ys * 18;
        int yy = oy0 - 1 + ys, xx = ox0 - 1 + xs;
        if (yy >= 0 && yy < HO && xx >= 0 && xx < WO)
          v = *(const u32x4*)(h1 + ((((size_t)b * HO + yy) * WO + xx) * COUT + cc * 32 + q * 8));
      }
      rg[i] = v;
    }
  };
  auto STORE = [&](unsigned int* buf) {
    #pragma unroll
    for (int i = 0; i < 6; ++i) {
      int e = i * 256 + tid;
      if (e < 1296) {
        int pos = e >> 2, q = e & 3;
        *(u32x4*)(buf + pos * 20 + q * 4) = rg[i];
      }
    }
  };

  LOAD(0);
  for (int cc = 0; cc < 2; ++cc) {
    if (cc) __syncthreads();
    STORE(&ldsA[cc & 1][0]);
    __syncthreads();
    if (cc < 1) LOAD(cc + 1);
    const unsigned int* buf = &ldsA[cc & 1][0];
    #pragma unroll
    for (int k = 0; k < 9; ++k) {
      const int dy = k / 3, dx = k - 3 * (k / 3);
      s16x8 b0 = Bb[((cc * 9 + k) * 4 + 0) * 64 + lane];
      s16x8 b1 = Bb[((cc * 9 + k) * 4 + 1) * 64 + lane];
      s16x8 b2 = Bb[((cc * 9 + k) * 4 + 2) * 64 + lane];
      s16x8 b3 = Bb[((cc * 9 + k) * 4 + 3) * 64 + lane];
      #pragma unroll
      for (int yi = 0; yi < 4; ++yi) {
        int row = (wv * 4 + yi + dy) * 18 + (lx + dx);
        s16x8 a = *(const s16x8*)((const char*)buf + (size_t)row * 80 + lg * 16);
        acc[yi][0] = __builtin_amdgcn_mfma_f32_16x16x32_bf16(a, b0, acc[yi][0], 0, 0, 0);
        acc[yi][1] = __builtin_amdgcn_mfma_f32_16x16x32_bf16(a, b1, acc[yi][1], 0, 0, 0);
        acc[yi][2] = __builtin_amdgcn_mfma_f32_16x16x32_bf16(a, b2, acc[yi][2], 0, 0, 0);
        acc[yi][3] = __builtin_amdgcn_mfma_f32_16x16x32_bf16(a, b3, acc[yi][3], 0, 0, 0);
      }
    }
  }
  const float her = 0.03f / 8.0f;
  #pragma unroll
  for (int yi = 0; yi < 4; ++yi) {
    int y = oy0 + wv * 4 + yi;
    f32x4_t nv = *(const f32x4_t*)(noise2 + (size_t)b * HO * WO + (size_t)y * WO + ox0 + lg * 4);
    float r[3][4];
    #pragma unroll
    for (int ch = 0; ch < 3; ++ch)
      #pragma unroll
      for (int jj = 0; jj < 4; ++jj) r[ch][jj] = 0.f;
    #pragma unroll
    for (int ot = 0; ot < 4; ++ot) {
      int o = ot * 16 + lx;
      float d = d2g[b * COUT + o], ba = baff2[o], bi = bias2[o];
      float w0 = rgbw[o], w1 = rgbw[COUT + o], w2 = rgbw[2 * COUT + o];
      f32x4_t hv;
      #pragma unroll
      for (int jj = 0; jj < 4; ++jj) {
        float v = acc[yi][ot][jj] * d + nv[jj] * ba + bi;
        v = lrelu(v);
        hv[jj] = v;
        r[0][jj] += w0 * v; r[1][jj] += w1 * v; r[2][jj] += w2 * v;
      }
      *(f32x4_t*)(hout + ((size_t)(b * COUT + o) * HO + y) * WO + ox0 + lg * 4) = hv;
    }
    #pragma unroll
    for (int ch = 0; ch < 3; ++ch)
      #pragma unroll
      for (int jj = 0; jj < 4; ++jj) {
        float s = r[ch][jj];
        s += __shfl_xor(s, 1); s += __shfl_xor(s, 2);
        s += __shfl_xor(s, 4); s += __shfl_xor(s, 8);
        r[ch][jj] = s;
      }
    if (lx < 12) {
      float val = 0.f;
      #pragma unroll
      for (int ii = 0; ii < 12; ++ii) if (lx == ii) val = r[ii >> 2][ii & 3];
      int ch = lx >> 2, jj = lx & 3;
      rgbout[(((size_t)(b * 3 + ch)) * HO + y) * WO + ox0 + lg * 4 + jj] = val * her + rgbb[ch];
    }
  }
}

extern "C" void kernel_launch(void* const* d_in, const int* in_sizes, int n_in,
                              void* d_out, int out_size, void* d_ws, size_t ws_size,
                              hipStream_t stream) {
  const float* x      = (const float*)d_in[0];
  const float* w      = (const float*)d_in[1];
  const float* c1w    = (const float*)d_in[2];
  const float* c2w    = (const float*)d_in[3];
  const float* bias1  = (const float*)d_in[4];
  const float* bias2  = (const float*)d_in[5];
  const float* a1w    = (const float*)d_in[6];
  const float* a1b    = (const float*)d_in[7];
  const float* a2w    = (const float*)d_in[8];
  const float* a2b    = (const float*)d_in[9];
  const float* baff1  = (const float*)d_in[10];
  const float* baff2  = (const float*)d_in[11];
  const float* rgbw   = (const float*)d_in[12];
  const float* rgbb   = (const float*)d_in[13];
  const float* noise1 = (const float*)d_in[14];
  const float* noise2 = (const float*)d_in[15];

  const size_t h1_bytes = (size_t)BN * HO * WO * COUT * 2;   // 32 MiB
  unsigned short* h1 = (unsigned short*)d_ws;
  char* p = (char*)d_ws + h1_bytes;
  float* s1  = (float*)p;               p += BN * CIN * 4;
  float* s2  = (float*)p;               p += BN * COUT * 4;
  float* d1g = (float*)p;               p += BN * COUT * 4;
  float* d2g = (float*)p;               p += BN * COUT * 4;
  unsigned short* B1pre = (unsigned short*)p;  p += 144 * 512 * 2;
  unsigned short* B2pre = (unsigned short*)p;

  // XU (bf16 channel-last, 64 MiB) lives in d_out; dead before conv2 writes hout.
  unsigned short* XU = (unsigned short*)d_out;
  float* hout   = (float*)d_out;
  float* rgbout = hout + (size_t)BN * COUT * HO * WO;

  k_prep<<<292, 256, 0, stream>>>(w, c1w, c2w, a1w, a1b, a2w, a2b, B1pre, B2pre, s1, s2, d1g, d2g);
  k_up<<<BN * HO, 256, 0, stream>>>(x, s1, XU);
  k_conv1<<<1024, 256, 0, stream>>>(XU, B1pre, noise1, bias1, baff1, d1g, s2, h1);
  k_conv2<<<1024, 256, 0, stream>>>(h1, B2pre, noise2, bias2, baff2, d2g, rgbw, rgbb, hout, rgbout);
}

// Round 8
// 142.516 us; speedup vs baseline: 1.4210x; 1.3602x over previous
//
#include <hip/hip_runtime.h>
#include <hip/hip_bf16.h>
#include <math.h>

#define BN 4
#define CIN 128
#define COUT 64
#define WSDIM 512
#define HI 128
#define WI 128
#define HO 256
#define WO 256
#define EPSC 1e-8f
#define GAINC 1.3867504905630728f
#define HE1 (GAINC/33.941125496954285f)
#define HE2 (GAINC/24.0f)
#define SUP (127.0f/255.0f)

typedef __attribute__((ext_vector_type(8))) short s16x8;
typedef __attribute__((ext_vector_type(4))) float f32x4_t;
typedef __attribute__((ext_vector_type(4))) unsigned int u32x4;

static __device__ __forceinline__ float lrelu(float v){ return v > 0.f ? v : 0.2f*v; }
static __device__ __forceinline__ unsigned short bfbits(float v){
  __hip_bfloat16 h = __float2bfloat16(v);
  return *reinterpret_cast<unsigned short*>(&h);
}
static __device__ __forceinline__ unsigned int packbf(float a, float b){
  return (unsigned int)bfbits(a) | ((unsigned int)bfbits(b) << 16);
}

// ---------------- fused prep: B-fragments (g<288) + styles/demod (g>=288) ----------------
// ROUND-6 VERBATIM (passing): o = ot*16 + (l&15)
__global__ __launch_bounds__(256) void k_prep(
    const float* __restrict__ w, const float* __restrict__ c1w, const float* __restrict__ c2w,
    const float* __restrict__ a1w, const float* __restrict__ a1b,
    const float* __restrict__ a2w, const float* __restrict__ a2b,
    unsigned short* __restrict__ B1, unsigned short* __restrict__ B2,
    float* __restrict__ s1, float* __restrict__ s2,
    float* __restrict__ d1g, float* __restrict__ d2g)
{
  const int g = blockIdx.x, t = threadIdx.x;
  __shared__ float sh1[CIN];
  __shared__ float sh2[COUT];
  if (g < 144) {
    int cc = g / 36, r = g - cc * 36, k = r >> 2, ot = r & 3;
    for (int e = t; e < 512; e += 256) {
      int l = e >> 3, j = e & 7;
      int c = cc * 32 + (l >> 4) * 8 + j, o = ot * 16 + (l & 15);
      B1[g * 512 + e] = bfbits(c1w[(c * COUT + o) * 9 + (8 - k)] * HE1);
    }
  } else if (g < 288) {
    int g2 = g - 144;
    int cc = g2 / 36, r = g2 - cc * 36, k = r >> 2, ot = r & 3;
    for (int e = t; e < 512; e += 256) {
      int l = e >> 3, j = e & 7;
      int c = cc * 32 + (l >> 4) * 8 + j, o = ot * 16 + (l & 15);
      B2[g2 * 512 + e] = bfbits(c2w[(c * COUT + o) * 9 + (8 - k)] * HE2);
    }
  } else {
    const int b = g - 288;
    const float he_a = 0.044194173824159216f;
    const float* wv = w + b * WSDIM;
    if (t < CIN) {
      float acc = 0.f;
      const float* ap = a1w + t * WSDIM;
      for (int k = 0; k < WSDIM; ++k) acc += ap[k] * wv[k];
      float v = acc * he_a + a1b[t];
      sh1[t] = v; s1[b * CIN + t] = v;
    } else if (t < CIN + COUT) {
      int o = t - CIN;
      float acc = 0.f;
      const float* ap = a2w + o * WSDIM;
      for (int k = 0; k < WSDIM; ++k) acc += ap[k] * wv[k];
      float v = acc * he_a + a2b[o];
      sh2[o] = v; s2[b * COUT + o] = v;
    }
    __syncthreads();
    const int o = t >> 2, p = t & 3;
    float acc = 0.f;
    for (int c = p * 32; c < p * 32 + 32; ++c) {
      const float* wp = c1w + (size_t)(c * COUT + o) * 9;
      float ws_ = 0.f;
      #pragma unroll
      for (int k = 0; k < 9; ++k) ws_ += wp[k] * wp[k];
      acc += sh1[c] * sh1[c] * ws_;
    }
    acc += __shfl_xor(acc, 1); acc += __shfl_xor(acc, 2);
    if (p == 0) d1g[b * COUT + o] = rsqrtf(acc * HE1 * HE1 + EPSC) * GAINC;
    float ac2 = 0.f;
    for (int c = p * 16; c < p * 16 + 16; ++c) {
      const float* wp = c2w + (size_t)(c * COUT + o) * 9;
      float ws_ = 0.f;
      #pragma unroll
      for (int k = 0; k < 9; ++k) ws_ += wp[k] * wp[k];
      ac2 += sh2[c] * sh2[c] * ws_;
    }
    ac2 += __shfl_xor(ac2, 1); ac2 += __shfl_xor(ac2, 2);
    if (p == 0) d2g[b * COUT + o] = rsqrtf(ac2 * HE2 * HE2 + EPSC) * GAINC;
  }
}

// ---------------- conv1: fused upsample staging (NEW) + ROUND-6 MFMA/epilogue ----------------
__global__ __launch_bounds__(256) void k_conv1(
    const float* __restrict__ x, const unsigned short* __restrict__ B1pre,
    const float* __restrict__ s1, const float* __restrict__ noise1,
    const float* __restrict__ bias1, const float* __restrict__ baff1,
    const float* __restrict__ d1g, const float* __restrict__ s2,
    unsigned short* __restrict__ h1)
{
  const int id = blockIdx.x;
  const int swz = (id & 7) * 128 + (id >> 3);
  const int b = swz >> 8;
  const int oy0 = ((swz >> 4) & 15) * 16, ox0 = (swz & 15) * 16;
  const int tid = threadIdx.x;
  const int lane = tid & 63, wv = tid >> 6;
  const int lx = lane & 15, lg = lane >> 4;

  __shared__ __align__(16) float patch[11 * 12 * 36];     // raw x tile [row][col][ch]
  __shared__ __align__(16) unsigned int ldsA[324 * 20];   // A tile, round-6 layout
  __shared__ float s1L[CIN];

  const int ty = oy0 > 0 ? oy0 - 1 : 0;
  const int tx = ox0 > 0 ? ox0 - 1 : 0;
  const int py0 = min((ty * 127) / 255, HI - 11);
  const int px0 = min((tx * 127) / 255, WI - 12);

  if (tid < CIN) s1L[tid] = s1[b * CIN + tid];

  f32x4_t acc[4][4];
  #pragma unroll
  for (int i = 0; i < 4; ++i)
    #pragma unroll
    for (int j = 0; j < 4; ++j) acc[i][j] = (f32x4_t){0.f, 0.f, 0.f, 0.f};

  float pr[5][4];
  auto PLOAD = [&](int cc) {
    #pragma unroll
    for (int i = 0; i < 5; ++i) {
      int u = tid + i * 256;
      if (u < 1056) {
        int pair = u / 3, part = u - pair * 3;
        int ch = pair & 31, r = pair >> 5;
        const float* src = x + (((size_t)b * CIN + cc * 32 + ch) << 14)
                             + (py0 + r) * WI + px0 + part * 4;
        pr[i][0] = src[0]; pr[i][1] = src[1]; pr[i][2] = src[2]; pr[i][3] = src[3];
      }
    }
  };
  auto PSTORE = [&]() {
    #pragma unroll
    for (int i = 0; i < 5; ++i) {
      int u = tid + i * 256;
      if (u < 1056) {
        int pair = u / 3, part = u - pair * 3;
        int ch = pair & 31, r = pair >> 5;
        float* dst = &patch[(r * 12 + part * 4) * 36 + ch];
        dst[0] = pr[i][0]; dst[36] = pr[i][1]; dst[72] = pr[i][2]; dst[108] = pr[i][3];
      }
    }
  };

  const s16x8* Bb = (const s16x8*)B1pre;

  PLOAD(0);
  for (int cc = 0; cc < 4; ++cc) {
    __syncthreads();                       // prev readers of patch/ldsA done (+s1L at cc=0)
    PSTORE();
    __syncthreads();                       // patch visible
    if (cc < 3) PLOAD(cc + 1);             // prefetch next chunk; hides under build+MFMA
    // ---- A-build: bilinear + modulate + bf16 pack (same ldsA layout as round 6) ----
    for (int e = tid; e < 1296; e += 256) {
      int pos = e >> 2, q = e & 3;
      int ys = pos / 18, xs = pos - ys * 18;
      int yy = oy0 - 1 + ys, xx = ox0 - 1 + xs;
      u32x4 outv = {0u, 0u, 0u, 0u};
      if (yy >= 0 && yy < HO && xx >= 0 && xx < WO) {
        float fy = yy * SUP; int y0 = (int)fy; float wy = fy - (float)y0;
        float fx = xx * SUP; int x0 = (int)fx; float wx = fx - (float)x0;
        int r0 = y0 - py0, r1 = min(y0 + 1, HI - 1) - py0;
        int c0 = x0 - px0, c1 = min(x0 + 1, WI - 1) - px0;
        const float* p00 = &patch[(r0 * 12 + c0) * 36 + q * 8];
        const float* p01 = &patch[(r0 * 12 + c1) * 36 + q * 8];
        const float* p10 = &patch[(r1 * 12 + c0) * 36 + q * 8];
        const float* p11 = &patch[(r1 * 12 + c1) * 36 + q * 8];
        unsigned int pk[4];
        #pragma unroll
        for (int h = 0; h < 2; ++h) {
          f32x4_t a00 = *(const f32x4_t*)(p00 + h * 4);
          f32x4_t a01 = *(const f32x4_t*)(p01 + h * 4);
          f32x4_t a10 = *(const f32x4_t*)(p10 + h * 4);
          f32x4_t a11 = *(const f32x4_t*)(p11 + h * 4);
          f32x4_t sv = *(const f32x4_t*)&s1L[cc * 32 + q * 8 + h * 4];
          float v[4];
          #pragma unroll
          for (int j = 0; j < 4; ++j) {
            float t0 = a00[j] + (a10[j] - a00[j]) * wy;
            float t1 = a01[j] + (a11[j] - a01[j]) * wy;
            v[j] = (t0 + (t1 - t0) * wx) * sv[j];
          }
          pk[h * 2 + 0] = packbf(v[0], v[1]);
          pk[h * 2 + 1] = packbf(v[2], v[3]);
        }
        outv = (u32x4){pk[0], pk[1], pk[2], pk[3]};
      }
      *(u32x4*)(ldsA + pos * 20 + q * 4) = outv;
    }
    __syncthreads();                       // A visible
    // ---- MFMA phase: ROUND-6 VERBATIM mapping ----
    #pragma unroll
    for (int k = 0; k < 9; ++k) {
      const int dy = k / 3, dx = k - 3 * (k / 3);
      s16x8 b0 = Bb[((cc * 9 + k) * 4 + 0) * 64 + lane];
      s16x8 b1 = Bb[((cc * 9 + k) * 4 + 1) * 64 + lane];
      s16x8 b2 = Bb[((cc * 9 + k) * 4 + 2) * 64 + lane];
      s16x8 b3 = Bb[((cc * 9 + k) * 4 + 3) * 64 + lane];
      #pragma unroll
      for (int yi = 0; yi < 4; ++yi) {
        int row = (wv * 4 + yi + dy) * 18 + (lx + dx);
        s16x8 a = *(const s16x8*)((const char*)ldsA + (size_t)row * 80 + lg * 16);
        acc[yi][0] = __builtin_amdgcn_mfma_f32_16x16x32_bf16(a, b0, acc[yi][0], 0, 0, 0);
        acc[yi][1] = __builtin_amdgcn_mfma_f32_16x16x32_bf16(a, b1, acc[yi][1], 0, 0, 0);
        acc[yi][2] = __builtin_amdgcn_mfma_f32_16x16x32_bf16(a, b2, acc[yi][2], 0, 0, 0);
        acc[yi][3] = __builtin_amdgcn_mfma_f32_16x16x32_bf16(a, b3, acc[yi][3], 0, 0, 0);
      }
    }
  }
  // ---- epilogue: ROUND-6 VERBATIM (o = ot*16+lx, pixel x = lg*4+jj) ----
  #pragma unroll
  for (int yi = 0; yi < 4; ++yi) {
    int y = oy0 + wv * 4 + yi;
    f32x4_t nv = *(const f32x4_t*)(noise1 + (size_t)b * HO * WO + (size_t)y * WO + ox0 + lg * 4);
    #pragma unroll
    for (int ot = 0; ot < 4; ++ot) {
      int o = ot * 16 + lx;
      float d = d1g[b * COUT + o], ba = baff1[o], bi = bias1[o], sv = s2[b * COUT + o];
      #pragma unroll
      for (int jj = 0; jj < 4; ++jj) {
        float v = acc[yi][ot][jj] * d + nv[jj] * ba + bi;
        v = lrelu(v) * sv;
        int xg = ox0 + lg * 4 + jj;
        h1[(((size_t)b * HO + y) * WO + xg) * COUT + o] = bfbits(v);
      }
    }
  }
}

// ---------------- conv2: ROUND-6 VERBATIM (passing) ----------------
__global__ __launch_bounds__(256, 3) void k_conv2(
    const unsigned short* __restrict__ h1, const unsigned short* __restrict__ B2pre,
    const float* __restrict__ noise2, const float* __restrict__ bias2, const float* __restrict__ baff2,
    const float* __restrict__ d2g, const float* __restrict__ rgbw, const float* __restrict__ rgbb,
    float* __restrict__ hout, float* __restrict__ rgbout)
{
  const int id = blockIdx.x;
  const int swz = (id & 7) * 128 + (id >> 3);
  const int b = swz >> 8;
  const int oy0 = ((swz >> 4) & 15) * 16, ox0 = (swz & 15) * 16;
  const int tid = threadIdx.x;
  const int lane = tid & 63, wv = tid >> 6;
  const int lx = lane & 15, lg = lane >> 4;

  __shared__ unsigned int ldsA[2][324 * 20];

  f32x4_t acc[4][4];
  #pragma unroll
  for (int i = 0; i < 4; ++i)
    #pragma unroll
    for (int j = 0; j < 4; ++j) acc[i][j] = (f32x4_t){0.f, 0.f, 0.f, 0.f};

  const s16x8* Bb = (const s16x8*)B2pre;

  u32x4 rg[6];
  auto LOAD = [&](int cc) {
    #pragma unroll
    for (int i = 0; i < 6; ++i) {
      int e = i * 256 + tid;
      u32x4 v = {0, 0, 0, 0};
      if (e < 1296) {
        int pos = e >> 2, q = e & 3;
        int ys = pos / 18, xs = pos - ys * 18;
        int yy = oy0 - 1 + ys, xx = ox0 - 1 + xs;
        if (yy >= 0 && yy < HO && xx >= 0 && xx < WO)
          v = *(const u32x4*)(h1 + ((((size_t)b * HO + yy) * WO + xx) * COUT + cc * 32 + q * 8));
      }
      rg[i] = v;
    }
  };
  auto STORE = [&](unsigned int* buf) {
    #pragma unroll
    for (int i = 0; i < 6; ++i) {
      int e = i * 256 + tid;
      if (e < 1296) {
        int pos = e >> 2, q = e & 3;
        *(u32x4*)(buf + pos * 20 + q * 4) = rg[i];
      }
    }
  };

  LOAD(0);
  for (int cc = 0; cc < 2; ++cc) {
    if (cc) __syncthreads();
    STORE(&ldsA[cc & 1][0]);
    __syncthreads();
    if (cc < 1) LOAD(cc + 1);
    const unsigned int* buf = &ldsA[cc & 1][0];
    #pragma unroll
    for (int k = 0; k < 9; ++k) {
      const int dy = k / 3, dx = k - 3 * (k / 3);
      s16x8 b0 = Bb[((cc * 9 + k) * 4 + 0) * 64 + lane];
      s16x8 b1 = Bb[((cc * 9 + k) * 4 + 1) * 64 + lane];
      s16x8 b2 = Bb[((cc * 9 + k) * 4 + 2) * 64 + lane];
      s16x8 b3 = Bb[((cc * 9 + k) * 4 + 3) * 64 + lane];
      #pragma unroll
      for (int yi = 0; yi < 4; ++yi) {
        int row = (wv * 4 + yi + dy) * 18 + (lx + dx);
        s16x8 a = *(const s16x8*)((const char*)buf + (size_t)row * 80 + lg * 16);
        acc[yi][0] = __builtin_amdgcn_mfma_f32_16x16x32_bf16(a, b0, acc[yi][0], 0, 0, 0);
        acc[yi][1] = __builtin_amdgcn_mfma_f32_16x16x32_bf16(a, b1, acc[yi][1], 0, 0, 0);
        acc[yi][2] = __builtin_amdgcn_mfma_f32_16x16x32_bf16(a, b2, acc[yi][2], 0, 0, 0);
        acc[yi][3] = __builtin_amdgcn_mfma_f32_16x16x32_bf16(a, b3, acc[yi][3], 0, 0, 0);
      }
    }
  }
  const float her = 0.03f / 8.0f;
  #pragma unroll
  for (int yi = 0; yi < 4; ++yi) {
    int y = oy0 + wv * 4 + yi;
    f32x4_t nv = *(const f32x4_t*)(noise2 + (size_t)b * HO * WO + (size_t)y * WO + ox0 + lg * 4);
    float r[3][4];
    #pragma unroll
    for (int ch = 0; ch < 3; ++ch)
      #pragma unroll
      for (int jj = 0; jj < 4; ++jj) r[ch][jj] = 0.f;
    #pragma unroll
    for (int ot = 0; ot < 4; ++ot) {
      int o = ot * 16 + lx;
      float d = d2g[b * COUT + o], ba = baff2[o], bi = bias2[o];
      float w0 = rgbw[o], w1 = rgbw[COUT + o], w2 = rgbw[2 * COUT + o];
      f32x4_t hv;
      #pragma unroll
      for (int jj = 0; jj < 4; ++jj) {
        float v = acc[yi][ot][jj] * d + nv[jj] * ba + bi;
        v = lrelu(v);
        hv[jj] = v;
        r[0][jj] += w0 * v; r[1][jj] += w1 * v; r[2][jj] += w2 * v;
      }
      *(f32x4_t*)(hout + ((size_t)(b * COUT + o) * HO + y) * WO + ox0 + lg * 4) = hv;
    }
    #pragma unroll
    for (int ch = 0; ch < 3; ++ch)
      #pragma unroll
      for (int jj = 0; jj < 4; ++jj) {
        float s = r[ch][jj];
        s += __shfl_xor(s, 1); s += __shfl_xor(s, 2);
        s += __shfl_xor(s, 4); s += __shfl_xor(s, 8);
        r[ch][jj] = s;
      }
    if (lx < 12) {
      float val = 0.f;
      #pragma unroll
      for (int ii = 0; ii < 12; ++ii) if (lx == ii) val = r[ii >> 2][ii & 3];
      int ch = lx >> 2, jj = lx & 3;
      rgbout[(((size_t)(b * 3 + ch)) * HO + y) * WO + ox0 + lg * 4 + jj] = val * her + rgbb[ch];
    }
  }
}

extern "C" void kernel_launch(void* const* d_in, const int* in_sizes, int n_in,
                              void* d_out, int out_size, void* d_ws, size_t ws_size,
                              hipStream_t stream) {
  const float* x      = (const float*)d_in[0];
  const float* w      = (const float*)d_in[1];
  const float* c1w    = (const float*)d_in[2];
  const float* c2w    = (const float*)d_in[3];
  const float* bias1  = (const float*)d_in[4];
  const float* bias2  = (const float*)d_in[5];
  const float* a1w    = (const float*)d_in[6];
  const float* a1b    = (const float*)d_in[7];
  const float* a2w    = (const float*)d_in[8];
  const float* a2b    = (const float*)d_in[9];
  const float* baff1  = (const float*)d_in[10];
  const float* baff2  = (const float*)d_in[11];
  const float* rgbw   = (const float*)d_in[12];
  const float* rgbb   = (const float*)d_in[13];
  const float* noise1 = (const float*)d_in[14];
  const float* noise2 = (const float*)d_in[15];

  const size_t h1_bytes = (size_t)BN * HO * WO * COUT * 2;   // 32 MiB
  unsigned short* h1 = (unsigned short*)d_ws;
  char* p = (char*)d_ws + h1_bytes;
  float* s1  = (float*)p;               p += BN * CIN * 4;
  float* s2  = (float*)p;               p += BN * COUT * 4;
  float* d1g = (float*)p;               p += BN * COUT * 4;
  float* d2g = (float*)p;               p += BN * COUT * 4;
  unsigned short* B1pre = (unsigned short*)p;  p += 144 * 512 * 2;
  unsigned short* B2pre = (unsigned short*)p;

  float* hout   = (float*)d_out;
  float* rgbout = hout + (size_t)BN * COUT * HO * WO;

  k_prep<<<292, 256, 0, stream>>>(w, c1w, c2w, a1w, a1b, a2w, a2b, B1pre, B2pre, s1, s2, d1g, d2g);
  k_conv1<<<1024, 256, 0, stream>>>(x, B1pre, s1, noise1, bias1, baff1, d1g, s2, h1);
  k_conv2<<<1024, 256, 0, stream>>>(h1, B2pre, noise2, bias2, baff2, d2g, rgbw, rgbb, hout, rgbout);
}

// Round 9
// 138.704 us; speedup vs baseline: 1.4600x; 1.0275x over previous
//
#include <hip/hip_runtime.h>
#include <hip/hip_bf16.h>
#include <math.h>

#define BN 4
#define CIN 128
#define COUT 64
#define WSDIM 512
#define HI 128
#define WI 128
#define HO 256
#define WO 256
#define EPSC 1e-8f
#define GAINC 1.3867504905630728f
#define HE1 (GAINC/33.941125496954285f)
#define HE2 (GAINC/24.0f)
#define SUP (127.0f/255.0f)

typedef __attribute__((ext_vector_type(8))) short s16x8;
typedef __attribute__((ext_vector_type(4))) float f32x4_t;
typedef __attribute__((ext_vector_type(4))) unsigned int u32x4;

static __device__ __forceinline__ float lrelu(float v){ return v > 0.f ? v : 0.2f*v; }
static __device__ __forceinline__ unsigned short bfbits(float v){
  __hip_bfloat16 h = __float2bfloat16(v);
  return *reinterpret_cast<unsigned short*>(&h);
}
static __device__ __forceinline__ unsigned int packbf(float a, float b){
  return (unsigned int)bfbits(a) | ((unsigned int)bfbits(b) << 16);
}
static __device__ __forceinline__ void gload_lds16(const void* g, void* l){
  __builtin_amdgcn_global_load_lds(
      (const __attribute__((address_space(1))) void*)g,
      (__attribute__((address_space(3))) void*)l, 16, 0, 0);
}

// ---------------- fused prep: B-fragments + styles/demod + zero page ----------------
__global__ __launch_bounds__(256) void k_prep(
    const float* __restrict__ w, const float* __restrict__ c1w, const float* __restrict__ c2w,
    const float* __restrict__ a1w, const float* __restrict__ a1b,
    const float* __restrict__ a2w, const float* __restrict__ a2b,
    unsigned short* __restrict__ B1, unsigned short* __restrict__ B2,
    float* __restrict__ s1, float* __restrict__ s2,
    float* __restrict__ d1g, float* __restrict__ d2g,
    unsigned int* __restrict__ zpage)
{
  const int g = blockIdx.x, t = threadIdx.x;
  __shared__ float sh1[CIN];
  __shared__ float sh2[COUT];
  if (g < 144) {
    if (g == 0 && t < 64) zpage[t] = 0u;     // 256B zero page for conv2 OOB lanes
    int cc = g / 36, r = g - cc * 36, k = r >> 2, ot = r & 3;
    for (int e = t; e < 512; e += 256) {
      int l = e >> 3, j = e & 7;
      int c = cc * 32 + (l >> 4) * 8 + j, o = ot * 16 + (l & 15);
      B1[g * 512 + e] = bfbits(c1w[(c * COUT + o) * 9 + (8 - k)] * HE1);
    }
  } else if (g < 288) {
    int g2 = g - 144;
    int cc = g2 / 36, r = g2 - cc * 36, k = r >> 2, ot = r & 3;
    for (int e = t; e < 512; e += 256) {
      int l = e >> 3, j = e & 7;
      int c = cc * 32 + (l >> 4) * 8 + j, o = ot * 16 + (l & 15);
      B2[g2 * 512 + e] = bfbits(c2w[(c * COUT + o) * 9 + (8 - k)] * HE2);
    }
  } else {
    const int b = g - 288;
    const float he_a = 0.044194173824159216f;
    const float* wv = w + b * WSDIM;
    if (t < CIN) {
      float acc = 0.f;
      const float* ap = a1w + t * WSDIM;
      for (int k = 0; k < WSDIM; ++k) acc += ap[k] * wv[k];
      float v = acc * he_a + a1b[t];
      sh1[t] = v; s1[b * CIN + t] = v;
    } else if (t < CIN + COUT) {
      int o = t - CIN;
      float acc = 0.f;
      const float* ap = a2w + o * WSDIM;
      for (int k = 0; k < WSDIM; ++k) acc += ap[k] * wv[k];
      float v = acc * he_a + a2b[o];
      sh2[o] = v; s2[b * COUT + o] = v;
    }
    __syncthreads();
    const int o = t >> 2, p = t & 3;
    float acc = 0.f;
    for (int c = p * 32; c < p * 32 + 32; ++c) {
      const float* wp = c1w + (size_t)(c * COUT + o) * 9;
      float ws_ = 0.f;
      #pragma unroll
      for (int k = 0; k < 9; ++k) ws_ += wp[k] * wp[k];
      acc += sh1[c] * sh1[c] * ws_;
    }
    acc += __shfl_xor(acc, 1); acc += __shfl_xor(acc, 2);
    if (p == 0) d1g[b * COUT + o] = rsqrtf(acc * HE1 * HE1 + EPSC) * GAINC;
    float ac2 = 0.f;
    for (int c = p * 16; c < p * 16 + 16; ++c) {
      const float* wp = c2w + (size_t)(c * COUT + o) * 9;
      float ws_ = 0.f;
      #pragma unroll
      for (int k = 0; k < 9; ++k) ws_ += wp[k] * wp[k];
      ac2 += sh2[c] * sh2[c] * ws_;
    }
    ac2 += __shfl_xor(ac2, 1); ac2 += __shfl_xor(ac2, 2);
    if (p == 0) d2g[b * COUT + o] = rsqrtf(ac2 * HE2 * HE2 + EPSC) * GAINC;
  }
}

// ---------------- conv1: fused upsample staging + implicit GEMM (unpadded A, s1-folded) ----------------
__global__ __launch_bounds__(256) void k_conv1(
    const float* __restrict__ x, const unsigned short* __restrict__ B1pre,
    const float* __restrict__ s1, const float* __restrict__ noise1,
    const float* __restrict__ bias1, const float* __restrict__ baff1,
    const float* __restrict__ d1g, const float* __restrict__ s2,
    unsigned short* __restrict__ h1)
{
  const int id = blockIdx.x;
  const int swz = (id & 7) * 128 + (id >> 3);
  const int b = swz >> 8;
  const int oy0 = ((swz >> 4) & 15) * 16, ox0 = (swz & 15) * 16;
  const int tid = threadIdx.x;
  const int lane = tid & 63, wv = tid >> 6;
  const int lx = lane & 15, lg = lane >> 4;

  __shared__ __align__(16) float patch[11 * 12 * 36];     // raw x tile [row][col][ch], s1 folded at store
  __shared__ __align__(16) unsigned int ldsA[324 * 16];   // A tile, 64B/pos (bank-balanced)
  __shared__ float s1L[CIN];

  const int ty = oy0 > 0 ? oy0 - 1 : 0;
  const int tx = ox0 > 0 ? ox0 - 1 : 0;
  const int py0 = min((ty * 127) / 255, HI - 11);
  const int px0 = min((tx * 127) / 255, WI - 12);

  if (tid < CIN) s1L[tid] = s1[b * CIN + tid];

  f32x4_t acc[4][4];
  #pragma unroll
  for (int i = 0; i < 4; ++i)
    #pragma unroll
    for (int j = 0; j < 4; ++j) acc[i][j] = (f32x4_t){0.f, 0.f, 0.f, 0.f};

  float pr[5][4];
  auto PLOAD = [&](int cc) {
    #pragma unroll
    for (int i = 0; i < 5; ++i) {
      int u = tid + i * 256;
      if (u < 1056) {
        int pair = u / 3, part = u - pair * 3;
        int ch = pair & 31, r = pair >> 5;
        const float* src = x + (((size_t)b * CIN + cc * 32 + ch) << 14)
                             + (py0 + r) * WI + px0 + part * 4;
        pr[i][0] = src[0]; pr[i][1] = src[1]; pr[i][2] = src[2]; pr[i][3] = src[3];
      }
    }
  };
  auto PSTORE = [&](int cc) {
    #pragma unroll
    for (int i = 0; i < 5; ++i) {
      int u = tid + i * 256;
      if (u < 1056) {
        int pair = u / 3, part = u - pair * 3;
        int ch = pair & 31, r = pair >> 5;
        float sv = s1L[cc * 32 + ch];
        float* dst = &patch[(r * 12 + part * 4) * 36 + ch];
        dst[0] = pr[i][0] * sv; dst[36] = pr[i][1] * sv;
        dst[72] = pr[i][2] * sv; dst[108] = pr[i][3] * sv;
      }
    }
  };

  const s16x8* Bb = (const s16x8*)B1pre;

  PLOAD(0);
  for (int cc = 0; cc < 4; ++cc) {
    __syncthreads();                       // prev readers of patch/ldsA done (+s1L at cc=0)
    PSTORE(cc);
    __syncthreads();                       // patch visible
    if (cc < 3) PLOAD(cc + 1);             // prefetch next chunk; hides under build+MFMA
    // ---- A-build: bilinear + bf16 pack (s1 already folded into patch) ----
    for (int e = tid; e < 1296; e += 256) {
      int pos = e >> 2, q = e & 3;
      int ys = pos / 18, xs = pos - ys * 18;
      int yy = oy0 - 1 + ys, xx = ox0 - 1 + xs;
      u32x4 outv = {0u, 0u, 0u, 0u};
      if (yy >= 0 && yy < HO && xx >= 0 && xx < WO) {
        float fy = yy * SUP; int y0 = (int)fy; float wy = fy - (float)y0;
        float fx = xx * SUP; int x0 = (int)fx; float wx = fx - (float)x0;
        int r0 = y0 - py0, r1 = min(y0 + 1, HI - 1) - py0;
        int c0 = x0 - px0, c1 = min(x0 + 1, WI - 1) - px0;
        const float* p00 = &patch[(r0 * 12 + c0) * 36 + q * 8];
        const float* p01 = &patch[(r0 * 12 + c1) * 36 + q * 8];
        const float* p10 = &patch[(r1 * 12 + c0) * 36 + q * 8];
        const float* p11 = &patch[(r1 * 12 + c1) * 36 + q * 8];
        unsigned int pk[4];
        #pragma unroll
        for (int h = 0; h < 2; ++h) {
          f32x4_t a00 = *(const f32x4_t*)(p00 + h * 4);
          f32x4_t a01 = *(const f32x4_t*)(p01 + h * 4);
          f32x4_t a10 = *(const f32x4_t*)(p10 + h * 4);
          f32x4_t a11 = *(const f32x4_t*)(p11 + h * 4);
          float v[4];
          #pragma unroll
          for (int j = 0; j < 4; ++j) {
            float t0 = a00[j] + (a10[j] - a00[j]) * wy;
            float t1 = a01[j] + (a11[j] - a01[j]) * wy;
            v[j] = t0 + (t1 - t0) * wx;
          }
          pk[h * 2 + 0] = packbf(v[0], v[1]);
          pk[h * 2 + 1] = packbf(v[2], v[3]);
        }
        outv = (u32x4){pk[0], pk[1], pk[2], pk[3]};
      }
      *(u32x4*)(ldsA + pos * 16 + q * 4) = outv;
    }
    __syncthreads();                       // A visible
    // ---- MFMA phase ----
    #pragma unroll
    for (int k = 0; k < 9; ++k) {
      const int dy = k / 3, dx = k - 3 * (k / 3);
      s16x8 b0 = Bb[((cc * 9 + k) * 4 + 0) * 64 + lane];
      s16x8 b1 = Bb[((cc * 9 + k) * 4 + 1) * 64 + lane];
      s16x8 b2 = Bb[((cc * 9 + k) * 4 + 2) * 64 + lane];
      s16x8 b3 = Bb[((cc * 9 + k) * 4 + 3) * 64 + lane];
      #pragma unroll
      for (int yi = 0; yi < 4; ++yi) {
        int row = (wv * 4 + yi + dy) * 18 + (lx + dx);
        s16x8 a = *(const s16x8*)((const char*)ldsA + (size_t)row * 64 + lg * 16);
        acc[yi][0] = __builtin_amdgcn_mfma_f32_16x16x32_bf16(a, b0, acc[yi][0], 0, 0, 0);
        acc[yi][1] = __builtin_amdgcn_mfma_f32_16x16x32_bf16(a, b1, acc[yi][1], 0, 0, 0);
        acc[yi][2] = __builtin_amdgcn_mfma_f32_16x16x32_bf16(a, b2, acc[yi][2], 0, 0, 0);
        acc[yi][3] = __builtin_amdgcn_mfma_f32_16x16x32_bf16(a, b3, acc[yi][3], 0, 0, 0);
      }
    }
  }
  // ---- epilogue (round-8 verbatim) ----
  #pragma unroll
  for (int yi = 0; yi < 4; ++yi) {
    int y = oy0 + wv * 4 + yi;
    f32x4_t nv = *(const f32x4_t*)(noise1 + (size_t)b * HO * WO + (size_t)y * WO + ox0 + lg * 4);
    #pragma unroll
    for (int ot = 0; ot < 4; ++ot) {
      int o = ot * 16 + lx;
      float d = d1g[b * COUT + o], ba = baff1[o], bi = bias1[o], sv = s2[b * COUT + o];
      #pragma unroll
      for (int jj = 0; jj < 4; ++jj) {
        float v = acc[yi][ot][jj] * d + nv[jj] * ba + bi;
        v = lrelu(v) * sv;
        int xg = ox0 + lg * 4 + jj;
        h1[(((size_t)b * HO + y) * WO + xg) * COUT + o] = bfbits(v);
      }
    }
  }
}

// ---------------- conv2: global_load_lds staging, 1 barrier + fused rgb ----------------
__global__ __launch_bounds__(256) void k_conv2(
    const unsigned short* __restrict__ h1, const unsigned short* __restrict__ B2pre,
    const float* __restrict__ noise2, const float* __restrict__ bias2, const float* __restrict__ baff2,
    const float* __restrict__ d2g, const float* __restrict__ rgbw, const float* __restrict__ rgbb,
    const unsigned int* __restrict__ zpage,
    float* __restrict__ hout, float* __restrict__ rgbout)
{
  const int id = blockIdx.x;
  const int swz = (id & 7) * 128 + (id >> 3);
  const int b = swz >> 8;
  const int oy0 = ((swz >> 4) & 15) * 16, ox0 = (swz & 15) * 16;
  const int tid = threadIdx.x;
  const int lane = tid & 63, wv = tid >> 6;
  const int lx = lane & 15, lg = lane >> 4;

  __shared__ __align__(16) unsigned int ldsA[2][1536 * 4];  // 2 x 24576B, 64B/pos + tail pad

  f32x4_t acc[4][4];
  #pragma unroll
  for (int i = 0; i < 4; ++i)
    #pragma unroll
    for (int j = 0; j < 4; ++j) acc[i][j] = (f32x4_t){0.f, 0.f, 0.f, 0.f};

  const s16x8* Bb = (const s16x8*)B2pre;

  // ---- issue both K-chunks via global_load_lds (dest linear: e*16B) ----
  const int e0u = __builtin_amdgcn_readfirstlane(tid & ~63);   // wave-uniform
  #pragma unroll
  for (int cc = 0; cc < 2; ++cc) {
    #pragma unroll
    for (int i = 0; i < 6; ++i) {
      int ebase = i * 256 + e0u;
      int e = ebase + lane;
      int pos = e >> 2, q = e & 3;
      int ys = pos / 18, xs = pos - ys * 18;
      int yy = oy0 - 1 + ys, xx = ox0 - 1 + xs;
      bool ok = (e < 1296) && (yy >= 0) && (yy < HO) && (xx >= 0) && (xx < WO);
      const void* src = ok
          ? (const void*)(h1 + ((((size_t)b * HO + yy) * WO + xx) * COUT) + cc * 32 + q * 8)
          : (const void*)zpage;
      gload_lds16(src, (void*)&ldsA[cc][(size_t)ebase * 4]);
    }
  }
  __syncthreads();   // implicit vmcnt(0) drain: both buffers ready

  #pragma unroll
  for (int cc = 0; cc < 2; ++cc) {
    const char* bufc = (const char*)ldsA[cc];
    #pragma unroll
    for (int k = 0; k < 9; ++k) {
      const int dy = k / 3, dx = k - 3 * (k / 3);
      s16x8 b0 = Bb[((cc * 9 + k) * 4 + 0) * 64 + lane];
      s16x8 b1 = Bb[((cc * 9 + k) * 4 + 1) * 64 + lane];
      s16x8 b2 = Bb[((cc * 9 + k) * 4 + 2) * 64 + lane];
      s16x8 b3 = Bb[((cc * 9 + k) * 4 + 3) * 64 + lane];
      #pragma unroll
      for (int yi = 0; yi < 4; ++yi) {
        int row = (wv * 4 + yi + dy) * 18 + (lx + dx);
        s16x8 a = *(const s16x8*)(bufc + (size_t)row * 64 + lg * 16);
        acc[yi][0] = __builtin_amdgcn_mfma_f32_16x16x32_bf16(a, b0, acc[yi][0], 0, 0, 0);
        acc[yi][1] = __builtin_amdgcn_mfma_f32_16x16x32_bf16(a, b1, acc[yi][1], 0, 0, 0);
        acc[yi][2] = __builtin_amdgcn_mfma_f32_16x16x32_bf16(a, b2, acc[yi][2], 0, 0, 0);
        acc[yi][3] = __builtin_amdgcn_mfma_f32_16x16x32_bf16(a, b3, acc[yi][3], 0, 0, 0);
      }
    }
  }
  // ---- epilogue (round-8 verbatim) ----
  const float her = 0.03f / 8.0f;
  #pragma unroll
  for (int yi = 0; yi < 4; ++yi) {
    int y = oy0 + wv * 4 + yi;
    f32x4_t nv = *(const f32x4_t*)(noise2 + (size_t)b * HO * WO + (size_t)y * WO + ox0 + lg * 4);
    float r[3][4];
    #pragma unroll
    for (int ch = 0; ch < 3; ++ch)
      #pragma unroll
      for (int jj = 0; jj < 4; ++jj) r[ch][jj] = 0.f;
    #pragma unroll
    for (int ot = 0; ot < 4; ++ot) {
      int o = ot * 16 + lx;
      float d = d2g[b * COUT + o], ba = baff2[o], bi = bias2[o];
      float w0 = rgbw[o], w1 = rgbw[COUT + o], w2 = rgbw[2 * COUT + o];
      f32x4_t hv;
      #pragma unroll
      for (int jj = 0; jj < 4; ++jj) {
        float v = acc[yi][ot][jj] * d + nv[jj] * ba + bi;
        v = lrelu(v);
        hv[jj] = v;
        r[0][jj] += w0 * v; r[1][jj] += w1 * v; r[2][jj] += w2 * v;
      }
      *(f32x4_t*)(hout + ((size_t)(b * COUT + o) * HO + y) * WO + ox0 + lg * 4) = hv;
    }
    #pragma unroll
    for (int ch = 0; ch < 3; ++ch)
      #pragma unroll
      for (int jj = 0; jj < 4; ++jj) {
        float s = r[ch][jj];
        s += __shfl_xor(s, 1); s += __shfl_xor(s, 2);
        s += __shfl_xor(s, 4); s += __shfl_xor(s, 8);
        r[ch][jj] = s;
      }
    if (lx < 12) {
      float val = 0.f;
      #pragma unroll
      for (int ii = 0; ii < 12; ++ii) if (lx == ii) val = r[ii >> 2][ii & 3];
      int ch = lx >> 2, jj = lx & 3;
      rgbout[(((size_t)(b * 3 + ch)) * HO + y) * WO + ox0 + lg * 4 + jj] = val * her + rgbb[ch];
    }
  }
}

extern "C" void kernel_launch(void* const* d_in, const int* in_sizes, int n_in,
                              void* d_out, int out_size, void* d_ws, size_t ws_size,
                              hipStream_t stream) {
  const float* x      = (const float*)d_in[0];
  const float* w      = (const float*)d_in[1];
  const float* c1w    = (const float*)d_in[2];
  const float* c2w    = (const float*)d_in[3];
  const float* bias1  = (const float*)d_in[4];
  const float* bias2  = (const float*)d_in[5];
  const float* a1w    = (const float*)d_in[6];
  const float* a1b    = (const float*)d_in[7];
  const float* a2w    = (const float*)d_in[8];
  const float* a2b    = (const float*)d_in[9];
  const float* baff1  = (const float*)d_in[10];
  const float* baff2  = (const float*)d_in[11];
  const float* rgbw   = (const float*)d_in[12];
  const float* rgbb   = (const float*)d_in[13];
  const float* noise1 = (const float*)d_in[14];
  const float* noise2 = (const float*)d_in[15];

  const size_t h1_bytes = (size_t)BN * HO * WO * COUT * 2;   // 32 MiB
  unsigned short* h1 = (unsigned short*)d_ws;
  char* p = (char*)d_ws + h1_bytes;
  float* s1  = (float*)p;               p += BN * CIN * 4;
  float* s2  = (float*)p;               p += BN * COUT * 4;
  float* d1g = (float*)p;               p += BN * COUT * 4;
  float* d2g = (float*)p;               p += BN * COUT * 4;
  unsigned short* B1pre = (unsigned short*)p;  p += 144 * 512 * 2;
  unsigned short* B2pre = (unsigned short*)p;  p += 144 * 512 * 2;
  unsigned int* zpage = (unsigned int*)p;

  float* hout   = (float*)d_out;
  float* rgbout = hout + (size_t)BN * COUT * HO * WO;

  k_prep<<<292, 256, 0, stream>>>(w, c1w, c2w, a1w, a1b, a2w, a2b, B1pre, B2pre, s1, s2, d1g, d2g, zpage);
  k_conv1<<<1024, 256, 0, stream>>>(x, B1pre, s1, noise1, bias1, baff1, d1g, s2, h1);
  k_conv2<<<1024, 256, 0, stream>>>(h1, B2pre, noise2, bias2, baff2, d2g, rgbw, rgbb, zpage, hout, rgbout);
}